// Round 1
// baseline (93.310 us; speedup 1.0000x reference)
//
#include <hip/hip_runtime.h>
#include <hip/hip_bf16.h>

// Problem: AggregationLoss. preds [32,6,256,256] f32, targets [32,2,256,256] i32.
// sim = preds[:,2:6]; text = targets[:,0]; kernel = targets[:,1]; MAX_T=16.
// Per sample: G[t] = mean of sim over kernel==t; per-pixel
// loss = log1p(max(||sim_p - G[text_p]|| - 0.5, 0)^2); per-instance mean over
// text==t for valid t (t>=1, k_cnt>0, t_cnt>0); output = mean over valid.

#define MAX_T 16
#define P_PIX 65536           // 256*256
#define NREP 8                // LDS histogram replication to cut atomic contention
#define STATS_F 96            // per-sample: k_cnt[16] | k_sum[16*4] | t_cnt[16]

// ws layout (floats): [32*96 stats][32*16 inst_sum]  = 3584 floats = 14336 B
#define WS_STATS_OFF 0
#define WS_ISUM_OFF (32 * STATS_F)
#define WS_TOTAL_F (WS_ISUM_OFF + 32 * MAX_T)

__global__ void agg_stats_kernel(const float* __restrict__ preds,
                                 const int* __restrict__ targets,
                                 float* __restrict__ ws) {
    const int s = blockIdx.y;
    __shared__ float h[NREP][STATS_F];
    for (int i = threadIdx.x; i < NREP * STATS_F; i += blockDim.x)
        ((float*)h)[i] = 0.0f;
    __syncthreads();

    const int copy = threadIdx.x & (NREP - 1);
    const float* sim  = preds + (size_t)s * 6 * P_PIX + 2 * (size_t)P_PIX;
    const int*   text = targets + (size_t)s * 2 * P_PIX;
    const int*   kern = text + P_PIX;

    const int stride = gridDim.x * blockDim.x;
    for (int p = blockIdx.x * blockDim.x + threadIdx.x; p < P_PIX; p += stride) {
        const int kb = kern[p];
        const int tb = text[p];
        const float s0 = sim[p];
        const float s1 = sim[p + P_PIX];
        const float s2 = sim[p + 2 * P_PIX];
        const float s3 = sim[p + 3 * P_PIX];
        atomicAdd(&h[copy][kb], 1.0f);
        atomicAdd(&h[copy][16 + kb * 4 + 0], s0);
        atomicAdd(&h[copy][16 + kb * 4 + 1], s1);
        atomicAdd(&h[copy][16 + kb * 4 + 2], s2);
        atomicAdd(&h[copy][16 + kb * 4 + 3], s3);
        atomicAdd(&h[copy][80 + tb], 1.0f);
    }
    __syncthreads();

    float* gstats = ws + WS_STATS_OFF + (size_t)s * STATS_F;
    for (int i = threadIdx.x; i < STATS_F; i += blockDim.x) {
        float v = 0.0f;
        #pragma unroll
        for (int c = 0; c < NREP; ++c) v += h[c][i];
        if (v != 0.0f) atomicAdd(&gstats[i], v);
    }
}

__global__ void agg_loss_kernel(const float* __restrict__ preds,
                                const int* __restrict__ targets,
                                float* __restrict__ ws) {
    const int s = blockIdx.y;
    __shared__ float G[MAX_T * 4];      // kernel-mean similarity vectors
    __shared__ float acc[NREP][MAX_T];

    const float* gstats = ws + WS_STATS_OFF + (size_t)s * STATS_F;
    if (threadIdx.x < MAX_T * 4) {
        const int t = threadIdx.x >> 2;
        const int c = threadIdx.x & 3;
        const float cnt = gstats[t];
        G[threadIdx.x] = gstats[16 + t * 4 + c] / fmaxf(cnt, 1.0f);
    }
    for (int i = threadIdx.x; i < NREP * MAX_T; i += blockDim.x)
        ((float*)acc)[i] = 0.0f;
    __syncthreads();

    const int copy = threadIdx.x & (NREP - 1);
    const float* sim  = preds + (size_t)s * 6 * P_PIX + 2 * (size_t)P_PIX;
    const int*   text = targets + (size_t)s * 2 * P_PIX;

    const int stride = gridDim.x * blockDim.x;
    for (int p = blockIdx.x * blockDim.x + threadIdx.x; p < P_PIX; p += stride) {
        const int tb = text[p];
        const float d0 = sim[p]             - G[tb * 4 + 0];
        const float d1 = sim[p + P_PIX]     - G[tb * 4 + 1];
        const float d2 = sim[p + 2 * P_PIX] - G[tb * 4 + 2];
        const float d3 = sim[p + 3 * P_PIX] - G[tb * 4 + 3];
        const float d = sqrtf(d0 * d0 + d1 * d1 + d2 * d2 + d3 * d3) - 0.5f;
        const float r = fmaxf(d, 0.0f);
        const float lp = log1pf(r * r);
        atomicAdd(&acc[copy][tb], lp);
    }
    __syncthreads();

    float* gisum = ws + WS_ISUM_OFF + (size_t)s * MAX_T;
    for (int i = threadIdx.x; i < MAX_T; i += blockDim.x) {
        float v = 0.0f;
        #pragma unroll
        for (int c = 0; c < NREP; ++c) v += acc[c][i];
        if (v != 0.0f) atomicAdd(&gisum[i], v);
    }
}

__global__ void agg_finalize_kernel(const float* __restrict__ ws,
                                    float* __restrict__ out) {
    const int s = blockIdx.x * blockDim.x + threadIdx.x;
    if (s >= 32) return;
    const float* gstats = ws + WS_STATS_OFF + (size_t)s * STATS_F;
    const float* gisum  = ws + WS_ISUM_OFF + (size_t)s * MAX_T;
    float total = 0.0f;
    float nvalid = 0.0f;
    for (int t = 1; t < MAX_T; ++t) {
        const float kc = gstats[t];
        const float tc = gstats[80 + t];
        if (kc > 0.0f && tc > 0.0f) {
            total += gisum[t] / tc;
            nvalid += 1.0f;
        }
    }
    out[s] = (nvalid > 0.0f) ? (total / nvalid) : 0.0f;
}

extern "C" void kernel_launch(void* const* d_in, const int* in_sizes, int n_in,
                              void* d_out, int out_size, void* d_ws, size_t ws_size,
                              hipStream_t stream) {
    const float* preds = (const float*)d_in[0];
    const int* targets = (const int*)d_in[1];
    float* out = (float*)d_out;
    float* ws = (float*)d_ws;

    // zero the accumulator region (harness poisons ws with 0xAA)
    hipMemsetAsync(ws, 0, WS_TOTAL_F * sizeof(float), stream);

    dim3 grid(64, 32);   // 64 blocks per sample, 32 samples
    dim3 block(256);
    agg_stats_kernel<<<grid, block, 0, stream>>>(preds, targets, ws);
    agg_loss_kernel<<<grid, block, 0, stream>>>(preds, targets, ws);
    agg_finalize_kernel<<<1, 64, 0, stream>>>(ws, out);
}

// Round 2
// 92.380 us; speedup vs baseline: 1.0101x; 1.0101x over previous
//
#include <hip/hip_runtime.h>
#include <hip/hip_bf16.h>

// AggregationLoss. preds [32,6,256,256] f32, targets [32,2,256,256] i32.
// sim = preds[:,2:6]; text = targets[:,0]; kernel = targets[:,1]; MAX_T=16.
// Per sample: G[t] = mean of sim over kernel==t; per-pixel
// loss = log1p(max(||sim_p - G[text_p]|| - 0.5, 0)^2); per-instance mean over
// text==t for valid t (t>=1, k_cnt>0, t_cnt>0); output = mean over valid.
//
// R2 design: NO global atomics (R1 post-mortem: 64-way same-line global atomic
// RMW serialization was ~66us). Each block writes a private non-atomic partial;
// the consumer kernel reduces partials. No memset needed (all slots written).

#define MAX_T 16
#define P_PIX 65536            // 256*256 pixels per sample
#define NS 32                  // samples
#define NB 32                  // blocks per sample (1024 blocks total = 4/CU)
#define STATS_F 96             // k_cnt[16] | k_sum[16*4] | t_cnt[16]
#define HPAD 97                // LDS copy stride (pad: 97%32=1 -> banks spread)

// ws layout (floats):
//   stats partials: [NS][NB][STATS_F]   = 98304 floats
//   isum  partials: [NS][NB][MAX_T]     = 16384 floats
#define WS_STATS_OFF 0
#define WS_ISUM_OFF (NS * NB * STATS_F)

__global__ __launch_bounds__(256) void agg_stats_kernel(
        const float* __restrict__ preds,
        const int* __restrict__ targets,
        float* __restrict__ ws) {
    const int s = blockIdx.y;
    const int b = blockIdx.x;
    __shared__ float h[64 * HPAD];
    for (int i = threadIdx.x; i < 64 * HPAD; i += 256) h[i] = 0.0f;
    __syncthreads();

    float* hc = h + (threadIdx.x & 63) * HPAD;   // one copy per lane
    const float* sim  = preds + (size_t)s * 6 * P_PIX + 2 * (size_t)P_PIX;
    const int*   text = targets + (size_t)s * 2 * P_PIX;
    const int*   kern = text + P_PIX;

    const int g = b * 256 + threadIdx.x;         // [0, 8192)
    #pragma unroll
    for (int it = 0; it < 2; ++it) {
        const int p4 = g + it * 8192;            // float4 index, [0, 16384)
        const int4  tb4 = ((const int4*)text)[p4];
        const int4  kb4 = ((const int4*)kern)[p4];
        const float4 v0 = ((const float4*)(sim))[p4];
        const float4 v1 = ((const float4*)(sim + P_PIX))[p4];
        const float4 v2 = ((const float4*)(sim + 2 * P_PIX))[p4];
        const float4 v3 = ((const float4*)(sim + 3 * P_PIX))[p4];

        #define PROC(kb, tb, a0, a1, a2, a3)                 \
            atomicAdd(&hc[(kb)], 1.0f);                      \
            atomicAdd(&hc[16 + (kb) * 4 + 0], (a0));         \
            atomicAdd(&hc[16 + (kb) * 4 + 1], (a1));         \
            atomicAdd(&hc[16 + (kb) * 4 + 2], (a2));         \
            atomicAdd(&hc[16 + (kb) * 4 + 3], (a3));         \
            atomicAdd(&hc[80 + (tb)], 1.0f);
        PROC(kb4.x, tb4.x, v0.x, v1.x, v2.x, v3.x)
        PROC(kb4.y, tb4.y, v0.y, v1.y, v2.y, v3.y)
        PROC(kb4.z, tb4.z, v0.z, v1.z, v2.z, v3.z)
        PROC(kb4.w, tb4.w, v0.w, v1.w, v2.w, v3.w)
        #undef PROC
    }
    __syncthreads();

    // non-atomic partial write: ws_stats[s][b][0..95]
    float* part = ws + WS_STATS_OFF + ((size_t)s * NB + b) * STATS_F;
    if (threadIdx.x < STATS_F) {
        float v = 0.0f;
        #pragma unroll
        for (int c = 0; c < 64; ++c) v += h[c * HPAD + threadIdx.x];
        part[threadIdx.x] = v;
    }
}

__global__ __launch_bounds__(256) void agg_loss_kernel(
        const float* __restrict__ preds,
        const int* __restrict__ targets,
        const float* __restrict__ ws_in,
        float* __restrict__ ws_out) {
    const int s = blockIdx.y;
    const int b = blockIdx.x;
    __shared__ float red[STATS_F];
    __shared__ float G[64];
    __shared__ float acc[64 * 17];

    // phase A: reduce the NB stats partials for this sample -> G
    if (threadIdx.x < STATS_F) {
        const float* base = ws_in + WS_STATS_OFF + (size_t)s * NB * STATS_F + threadIdx.x;
        float v = 0.0f;
        #pragma unroll 4
        for (int pb = 0; pb < NB; ++pb) v += base[pb * STATS_F];
        red[threadIdx.x] = v;
    }
    for (int i = threadIdx.x; i < 64 * 17; i += 256) acc[i] = 0.0f;
    __syncthreads();
    if (threadIdx.x < 64) {
        const float cnt = red[threadIdx.x >> 2];
        G[threadIdx.x] = red[16 + threadIdx.x] / fmaxf(cnt, 1.0f);
    }
    __syncthreads();

    float* ac = acc + (threadIdx.x & 63) * 17;
    const float* sim  = preds + (size_t)s * 6 * P_PIX + 2 * (size_t)P_PIX;
    const int*   text = targets + (size_t)s * 2 * P_PIX;

    const int g = b * 256 + threadIdx.x;
    #pragma unroll
    for (int it = 0; it < 2; ++it) {
        const int p4 = g + it * 8192;
        const int4  tb4 = ((const int4*)text)[p4];
        const float4 v0 = ((const float4*)(sim))[p4];
        const float4 v1 = ((const float4*)(sim + P_PIX))[p4];
        const float4 v2 = ((const float4*)(sim + 2 * P_PIX))[p4];
        const float4 v3 = ((const float4*)(sim + 3 * P_PIX))[p4];

        #define PROC(tb, a0, a1, a2, a3)                                   \
            {                                                              \
                const float d0 = (a0) - G[(tb) * 4 + 0];                   \
                const float d1 = (a1) - G[(tb) * 4 + 1];                   \
                const float d2 = (a2) - G[(tb) * 4 + 2];                   \
                const float d3 = (a3) - G[(tb) * 4 + 3];                   \
                const float d = sqrtf(d0*d0 + d1*d1 + d2*d2 + d3*d3) - 0.5f; \
                const float r = fmaxf(d, 0.0f);                            \
                atomicAdd(&ac[(tb)], log1pf(r * r));                       \
            }
        PROC(tb4.x, v0.x, v1.x, v2.x, v3.x)
        PROC(tb4.y, v0.y, v1.y, v2.y, v3.y)
        PROC(tb4.z, v0.z, v1.z, v2.z, v3.z)
        PROC(tb4.w, v0.w, v1.w, v2.w, v3.w)
        #undef PROC
    }
    __syncthreads();

    // non-atomic partial write: ws_isum[s][b][0..15]
    float* part = ws_out + WS_ISUM_OFF + ((size_t)s * NB + b) * MAX_T;
    if (threadIdx.x < MAX_T) {
        float v = 0.0f;
        #pragma unroll
        for (int c = 0; c < 64; ++c) v += acc[c * 17 + threadIdx.x];
        part[threadIdx.x] = v;
    }
}

__global__ __launch_bounds__(512) void agg_finalize_kernel(
        const float* __restrict__ ws, float* __restrict__ out) {
    const int tid = threadIdx.x;       // 512 = 32 samples * 16 bins
    const int s = tid >> 4;
    const int t = tid & 15;
    float kc = 0.0f, tc = 0.0f, is = 0.0f;
    #pragma unroll 4
    for (int pb = 0; pb < NB; ++pb) {
        const float* st = ws + WS_STATS_OFF + ((size_t)s * NB + pb) * STATS_F;
        kc += st[t];
        tc += st[80 + t];
        is += ws[WS_ISUM_OFF + ((size_t)s * NB + pb) * MAX_T + t];
    }
    const bool valid = (t >= 1) && (kc > 0.0f) && (tc > 0.0f);
    float im = valid ? is / fmaxf(tc, 1.0f) : 0.0f;
    float nv = valid ? 1.0f : 0.0f;
    #pragma unroll
    for (int m = 8; m >= 1; m >>= 1) {
        im += __shfl_xor(im, m, 16);
        nv += __shfl_xor(nv, m, 16);
    }
    if (t == 0) out[s] = (nv > 0.0f) ? (im / nv) : 0.0f;
}

extern "C" void kernel_launch(void* const* d_in, const int* in_sizes, int n_in,
                              void* d_out, int out_size, void* d_ws, size_t ws_size,
                              hipStream_t stream) {
    const float* preds = (const float*)d_in[0];
    const int* targets = (const int*)d_in[1];
    float* out = (float*)d_out;
    float* ws = (float*)d_ws;

    dim3 grid(NB, NS);
    agg_stats_kernel<<<grid, 256, 0, stream>>>(preds, targets, ws);
    agg_loss_kernel<<<grid, 256, 0, stream>>>(preds, targets, ws, ws);
    agg_finalize_kernel<<<1, 512, 0, stream>>>(ws, out);
}

// Round 3
// 50.273 us; speedup vs baseline: 1.8561x; 1.8375x over previous
//
#include <hip/hip_runtime.h>
#include <hip/hip_bf16.h>

// AggregationLoss. preds [32,6,256,256] f32, targets [32,2,256,256] i32.
// sim = preds[:,2:6]; text = targets[:,0]; kernel = targets[:,1]; MAX_T=16.
// Per sample: G[t] = mean of sim over kernel==t; per-pixel
// loss = log1p(max(||sim_p - G[text_p]|| - 0.5, 0)^2); per-instance mean over
// text==t for valid t (t>=1, k_cnt>0, t_cnt>0); output = mean over valid.
//
// R3 design: NO atomics at all (R1: global-atomic serialization theory WRONG;
// R2: LDS-atomic RMW occupancy is the real ~200cyc/instr bottleneck).
// Register accumulators with 15-bin predicated adds (bin 0 = background is
// never valid -> dropped), wave shfl reduce, plain-store partials, consumer
// reduces partials. No ws pre-zero needed (every slot read is written).

#define P_PIX 65536
#define NS 32
#define NB 16                 // blocks per sample; 512 blocks total
#define NBINS 15              // instance bins 1..15
#define SP_F 96               // stats partial stride: kcnt[0..14] ksum[15..74] tcnt[75..89]

#define WS_STATS_OFF 0
#define WS_ISUM_OFF (NS * NB * SP_F)   // isum partials: [NS][NB][16]

__global__ __launch_bounds__(256) void agg_stats_kernel(
        const float* __restrict__ preds,
        const int* __restrict__ targets,
        float* __restrict__ ws) {
    const int s = blockIdx.y;
    const int b = blockIdx.x;

    float kcnt[NBINS], tcnt[NBINS], ksum[NBINS * 4];
    #pragma unroll
    for (int k = 0; k < NBINS; ++k) { kcnt[k] = 0.0f; tcnt[k] = 0.0f; }
    #pragma unroll
    for (int k = 0; k < NBINS * 4; ++k) ksum[k] = 0.0f;

    const float* sim  = preds + (size_t)s * 6 * P_PIX + 2 * (size_t)P_PIX;
    const int*   text = targets + (size_t)s * 2 * P_PIX;
    const int*   kern = text + P_PIX;

    #pragma unroll
    for (int it = 0; it < 4; ++it) {
        const int p4 = b * 1024 + it * 256 + threadIdx.x;   // float4 index
        const int4   tb4 = ((const int4*)text)[p4];
        const int4   kb4 = ((const int4*)kern)[p4];
        const float4 v0 = ((const float4*)(sim))[p4];
        const float4 v1 = ((const float4*)(sim + P_PIX))[p4];
        const float4 v2 = ((const float4*)(sim + 2 * P_PIX))[p4];
        const float4 v3 = ((const float4*)(sim + 3 * P_PIX))[p4];
        const int tbv[4] = {tb4.x, tb4.y, tb4.z, tb4.w};
        const int kbv[4] = {kb4.x, kb4.y, kb4.z, kb4.w};
        const float a[4][4] = {{v0.x, v1.x, v2.x, v3.x}, {v0.y, v1.y, v2.y, v3.y},
                               {v0.z, v1.z, v2.z, v3.z}, {v0.w, v1.w, v2.w, v3.w}};
        #pragma unroll
        for (int j = 0; j < 4; ++j) {
            #pragma unroll
            for (int t = 1; t < 16; ++t) {
                const float mk = (kbv[j] == t) ? 1.0f : 0.0f;
                const float mt = (tbv[j] == t) ? 1.0f : 0.0f;
                kcnt[t - 1] += mk;
                tcnt[t - 1] += mt;
                #pragma unroll
                for (int c = 0; c < 4; ++c)
                    ksum[(t - 1) * 4 + c] = fmaf(mk, a[j][c], ksum[(t - 1) * 4 + c]);
            }
        }
    }

    // wave reduce to lane 0
    #pragma unroll
    for (int off = 32; off >= 1; off >>= 1) {
        #pragma unroll
        for (int k = 0; k < NBINS; ++k) {
            kcnt[k] += __shfl_down(kcnt[k], off);
            tcnt[k] += __shfl_down(tcnt[k], off);
        }
        #pragma unroll
        for (int k = 0; k < NBINS * 4; ++k) ksum[k] += __shfl_down(ksum[k], off);
    }

    __shared__ float wred[4][SP_F];
    if ((threadIdx.x & 63) == 0) {
        const int w = threadIdx.x >> 6;
        #pragma unroll
        for (int k = 0; k < NBINS; ++k) { wred[w][k] = kcnt[k]; wred[w][75 + k] = tcnt[k]; }
        #pragma unroll
        for (int k = 0; k < NBINS * 4; ++k) wred[w][15 + k] = ksum[k];
    }
    __syncthreads();
    if (threadIdx.x < 90) {
        float* part = ws + WS_STATS_OFF + ((size_t)s * NB + b) * SP_F;
        part[threadIdx.x] = wred[0][threadIdx.x] + wred[1][threadIdx.x] +
                            wred[2][threadIdx.x] + wred[3][threadIdx.x];
    }
}

__global__ __launch_bounds__(256) void agg_loss_kernel(
        const float* __restrict__ preds,
        const int* __restrict__ targets,
        float* __restrict__ ws) {
    const int s = blockIdx.y;
    const int b = blockIdx.x;

    __shared__ float tmp[75];
    __shared__ __align__(16) float G[60];   // G[(t-1)*4 + c], bins 1..15
    if (threadIdx.x < 75) {
        const float* base = ws + WS_STATS_OFF + (size_t)s * NB * SP_F + threadIdx.x;
        float v = 0.0f;
        #pragma unroll
        for (int pb = 0; pb < NB; ++pb) v += base[pb * SP_F];
        tmp[threadIdx.x] = v;
    }
    __syncthreads();
    if (threadIdx.x < 60)
        G[threadIdx.x] = tmp[15 + threadIdx.x] / fmaxf(tmp[threadIdx.x >> 2], 1.0f);
    __syncthreads();

    float isum[NBINS];
    #pragma unroll
    for (int k = 0; k < NBINS; ++k) isum[k] = 0.0f;

    const float* sim  = preds + (size_t)s * 6 * P_PIX + 2 * (size_t)P_PIX;
    const int*   text = targets + (size_t)s * 2 * P_PIX;

    #pragma unroll
    for (int it = 0; it < 4; ++it) {
        const int p4 = b * 1024 + it * 256 + threadIdx.x;
        const int4   tb4 = ((const int4*)text)[p4];
        const float4 v0 = ((const float4*)(sim))[p4];
        const float4 v1 = ((const float4*)(sim + P_PIX))[p4];
        const float4 v2 = ((const float4*)(sim + 2 * P_PIX))[p4];
        const float4 v3 = ((const float4*)(sim + 3 * P_PIX))[p4];
        const int tbv[4] = {tb4.x, tb4.y, tb4.z, tb4.w};
        const float a[4][4] = {{v0.x, v1.x, v2.x, v3.x}, {v0.y, v1.y, v2.y, v3.y},
                               {v0.z, v1.z, v2.z, v3.z}, {v0.w, v1.w, v2.w, v3.w}};
        #pragma unroll
        for (int j = 0; j < 4; ++j) {
            const int tb = tbv[j];
            const int gi = ((tb > 0) ? (tb - 1) : 0) * 4;    // tb==0 -> discarded below
            const float4 g = *(const float4*)&G[gi];
            const float d0 = a[j][0] - g.x;
            const float d1 = a[j][1] - g.y;
            const float d2 = a[j][2] - g.z;
            const float d3 = a[j][3] - g.w;
            const float dd = sqrtf(d0 * d0 + d1 * d1 + d2 * d2 + d3 * d3) - 0.5f;
            const float r = fmaxf(dd, 0.0f);
            const float lp = log1pf(r * r);
            #pragma unroll
            for (int t = 1; t < 16; ++t) isum[t - 1] += (tb == t) ? lp : 0.0f;
        }
    }

    #pragma unroll
    for (int off = 32; off >= 1; off >>= 1) {
        #pragma unroll
        for (int k = 0; k < NBINS; ++k) isum[k] += __shfl_down(isum[k], off);
    }

    __shared__ float iw[4][16];
    if ((threadIdx.x & 63) == 0) {
        const int w = threadIdx.x >> 6;
        #pragma unroll
        for (int k = 0; k < NBINS; ++k) iw[w][k] = isum[k];
    }
    __syncthreads();
    if (threadIdx.x < NBINS) {
        float* part = ws + WS_ISUM_OFF + ((size_t)s * NB + b) * 16;
        part[threadIdx.x] = iw[0][threadIdx.x] + iw[1][threadIdx.x] +
                            iw[2][threadIdx.x] + iw[3][threadIdx.x];
    }
}

__global__ __launch_bounds__(512) void agg_finalize_kernel(
        const float* __restrict__ ws, float* __restrict__ out) {
    const int tid = threadIdx.x;       // 512 = 32 samples * 16 lanes
    const int s = tid >> 4;
    const int t = tid & 15;            // t = bin-1 index; lane 15 inactive
    float kc = 0.0f, tc = 0.0f, is = 0.0f;
    if (t < NBINS) {
        #pragma unroll 4
        for (int pb = 0; pb < NB; ++pb) {
            const float* st = ws + WS_STATS_OFF + ((size_t)s * NB + pb) * SP_F;
            kc += st[t];
            tc += st[75 + t];
            is += ws[WS_ISUM_OFF + ((size_t)s * NB + pb) * 16 + t];
        }
    }
    const bool valid = (t < NBINS) && (kc > 0.0f) && (tc > 0.0f);
    float im = valid ? is / tc : 0.0f;
    float nv = valid ? 1.0f : 0.0f;
    #pragma unroll
    for (int m = 8; m >= 1; m >>= 1) {
        im += __shfl_xor(im, m, 16);
        nv += __shfl_xor(nv, m, 16);
    }
    if (t == 0) out[s] = (nv > 0.0f) ? (im / nv) : 0.0f;
}

extern "C" void kernel_launch(void* const* d_in, const int* in_sizes, int n_in,
                              void* d_out, int out_size, void* d_ws, size_t ws_size,
                              hipStream_t stream) {
    const float* preds = (const float*)d_in[0];
    const int* targets = (const int*)d_in[1];
    float* out = (float*)d_out;
    float* ws = (float*)d_ws;

    dim3 grid(NB, NS);
    agg_stats_kernel<<<grid, 256, 0, stream>>>(preds, targets, ws);
    agg_loss_kernel<<<grid, 256, 0, stream>>>(preds, targets, ws);
    agg_finalize_kernel<<<1, 512, 0, stream>>>(ws, out);
}